// Round 1
// baseline (178641.016 us; speedup 1.0000x reference)
//
#include <hip/hip_runtime.h>
#include <hip/hip_bf16.h>
#include <stdint.h>

#define NCU 256
#define TPB 512

#define IN_DIM 1024
#define HID1   1024
#define HID2   2048
#define T_STEPS 2048
#define G2 (4*HID2)   // 8192 layer-2 gate rows

__device__ __forceinline__ float bf_lo(uint32_t u){ return __uint_as_float(u << 16); }
__device__ __forceinline__ float bf_hi(uint32_t u){ return __uint_as_float(u & 0xffff0000u); }
__device__ __forceinline__ uint16_t f2bf(float f){
  uint32_t x = __float_as_uint(f);
  return (uint16_t)((x + 0x7fffu + ((x >> 16) & 1u)) >> 16);   // RNE
}

__device__ __forceinline__ float wave_reduce(float v){
  v += __shfl_xor(v, 32);
  v += __shfl_xor(v, 16);
  v += __shfl_xor(v, 8);
  v += __shfl_xor(v, 4);
  v += __shfl_xor(v, 2);
  v += __shfl_xor(v, 1);
  return v;
}

__device__ __forceinline__ float sigmoidf_(float x){ return 1.0f / (1.0f + expf(-x)); }

// ---------------------------------------------------------------------------
// prep: convert Wih2 fp32 -> packed bf16 pairs in ws; zero sync state.
// Runs every launch (replay-deterministic).
// ---------------------------------------------------------------------------
__global__ void prep_kernel(const float* __restrict__ Wih2, uint32_t* __restrict__ wih2_bf,
                            float* __restrict__ h1_buf, float* __restrict__ h2_buf,
                            int* __restrict__ flag1, int* __restrict__ flag2)
{
  int64_t idx    = (int64_t)blockIdx.x * blockDim.x + threadIdx.x;
  int64_t stride = (int64_t)gridDim.x * blockDim.x;
  const int64_t NW = (int64_t)G2 * IN_DIM / 2;   // dwords (2 bf16 each)
  for (int64_t j = idx; j < NW; j += stride) {
    float a = Wih2[2*j], b = Wih2[2*j+1];
    wih2_bf[j] = (uint32_t)f2bf(a) | ((uint32_t)f2bf(b) << 16);
  }
  for (int64_t j = idx; j < 2*HID1; j += stride) h1_buf[j] = 0.f;
  for (int64_t j = idx; j < 2*HID2; j += stride) h2_buf[j] = 0.f;
  for (int64_t j = idx; j < NCU;    j += stride) { flag1[j] = 0; flag2[j] = 0; }
}

// ---------------------------------------------------------------------------
// persistent 2-layer LSTM scan. 256 blocks (1/CU) x 512 threads.
// Block b owns layer1 units [4b,4b+4) and layer2 units [8b,8b+8).
// ---------------------------------------------------------------------------
__global__ __launch_bounds__(TPB, 1) void lstm_persist(
    const float* __restrict__ x,    const float* __restrict__ Wih1,
    const float* __restrict__ Whh1, const float* __restrict__ b1,
    const float* __restrict__ Whh2, const float* __restrict__ b2,
    const float* __restrict__ Wout,
    const uint32_t* __restrict__ wih2_bf,
    float* __restrict__ h1_buf, float* __restrict__ h2_buf,
    int* __restrict__ flag1, int* __restrict__ flag2,
    float* __restrict__ partial_out)
{
  // 128 KiB: 32 rows x 2048 bf16 (dword-packed, row stride 1024 dwords -> 2-way free)
  __shared__ uint32_t whh2_lds[32 * 1024];
  __shared__ float h1_loc[HID1];   // gathered h1_t (4 KiB)
  __shared__ float h2_loc[HID2];   // gathered h2_{t-1} (8 KiB)
  __shared__ float gsum1[16], gx1v[16], c1v[4];
  __shared__ float gsum2[32], b2v[32], c2v[8], h2own[8], woutv[8];

  const int b    = blockIdx.x;
  const int tid  = threadIdx.x;
  const int lane = tid & 63;
  const int wv   = tid >> 6;   // 8 waves

  // ---- init: stage Whh2 slice into LDS (fp32 -> bf16 inline) ----
  for (int i = tid; i < 32 * 1024; i += TPB) {       // i = dword index
    int lr = i >> 10, dw = i & 1023;
    int g = lr >> 3, uu = lr & 7;
    int64_t row = (int64_t)(g * HID2 + 8 * b + uu);
    const float* src = Whh2 + row * HID2 + 2 * dw;
    whh2_lds[i] = (uint32_t)f2bf(src[0]) | ((uint32_t)f2bf(src[1]) << 16);
  }

  // ---- Whh1 slice in registers (fp32, 2 rows/wave, 16 elems/lane/row) ----
  float w1r[2][16];
  int rows1[2];
  for (int rr = 0; rr < 2; ++rr) {
    int lr1 = wv * 2 + rr;
    int g = lr1 >> 2, uu = lr1 & 3;
    int row = g * HID1 + 4 * b + uu;
    rows1[rr] = row;
    #pragma unroll
    for (int j = 0; j < 16; ++j)
      w1r[rr][j] = Whh1[(int64_t)row * IN_DIM + lane + 64 * j];
  }

  // ---- gx1 = Wih1 @ x + b1 (constant over t: x is identical every step) ----
  for (int rr = 0; rr < 2; ++rr) {
    int row = rows1[rr];
    float s = 0.f;
    #pragma unroll
    for (int j = 0; j < 16; ++j)
      s += Wih1[(int64_t)row * IN_DIM + lane + 64 * j] * x[lane + 64 * j];
    s = wave_reduce(s);
    if (lane == 0) gx1v[wv * 2 + rr] = s + b1[row];
  }
  if (tid < 32) { int g = tid >> 3, uu = tid & 7; b2v[tid] = b2[g * HID2 + 8 * b + uu]; }
  if (tid < 8)  { woutv[tid] = Wout[8 * b + tid]; c2v[tid] = 0.f; h2own[tid] = 0.f; }
  if (tid < 4)  { c1v[tid] = 0.f; }
  for (int i = tid; i < HID1; i += TPB) h1_loc[i] = 0.f;
  for (int i = tid; i < HID2; i += TPB) h2_loc[i] = 0.f;
  __syncthreads();

  // ---- time loop ----
  for (int t = 0; t < T_STEPS; ++t) {
    const int par = t & 1;
    const int target = t + 1;

    // ---- Phase A: layer1 recurrent matvec (h1_loc = h1_{t-1}) ----
    #pragma unroll
    for (int rr = 0; rr < 2; ++rr) {
      float s = 0.f;
      #pragma unroll
      for (int j = 0; j < 16; ++j) s += w1r[rr][j] * h1_loc[lane + 64 * j];
      s = wave_reduce(s);
      if (lane == 0) gsum1[wv * 2 + rr] = s;
    }
    __syncthreads();
    if (tid < 4) {
      int uu = tid;
      float gi = sigmoidf_(gsum1[uu]      + gx1v[uu]);
      float gf = sigmoidf_(gsum1[4 + uu]  + gx1v[4 + uu]);
      float gg = tanhf    (gsum1[8 + uu]  + gx1v[8 + uu]);
      float go = sigmoidf_(gsum1[12 + uu] + gx1v[12 + uu]);
      float c = gf * c1v[uu] + gi * gg;
      c1v[uu] = c;
      float h = go * tanhf(c);
      h1_buf[par * HID1 + 4 * b + uu] = h;          // plain store
    }
    __syncthreads();                                 // drains each wave's vmcnt
    if (tid == 0) {
      __threadfence();                               // wb L2 -> coherence point
      __hip_atomic_store(&flag1[b], target, __ATOMIC_RELEASE, __HIP_MEMORY_SCOPE_AGENT);
    }
    if (tid < NCU) {
      while (__hip_atomic_load(&flag1[tid], __ATOMIC_RELAXED, __HIP_MEMORY_SCOPE_AGENT) < target)
        __builtin_amdgcn_s_sleep(2);
    }
    __syncthreads();
    __threadfence();                                 // invalidate stale L1/L2
    {
      const float2* src = (const float2*)(h1_buf + par * HID1);
      float2* dst = (float2*)h1_loc;
      for (int i = tid; i < HID1 / 2; i += TPB) dst[i] = src[i];
    }
    __syncthreads();

    // ---- Phase B: layer2 matvec: Wih2 (L2-stream bf16) + Whh2 (LDS bf16) ----
    #pragma unroll
    for (int rr = 0; rr < 4; ++rr) {
      int lr = wv * 4 + rr;
      int g = lr >> 3, uu = lr & 7;
      int64_t row = (int64_t)(g * HID2 + 8 * b + uu);
      float s = 0.f;
      const uint4*  wi  = (const uint4*)(wih2_bf + row * (IN_DIM / 2));
      const float4* h1p = (const float4*)h1_loc;
      #pragma unroll
      for (int q = 0; q < 2; ++q) {
        uint4  w  = wi[lane + 64 * q];
        float4 ha = h1p[2 * (lane + 64 * q)];
        float4 hb = h1p[2 * (lane + 64 * q) + 1];
        s += bf_lo(w.x)*ha.x + bf_hi(w.x)*ha.y + bf_lo(w.y)*ha.z + bf_hi(w.y)*ha.w;
        s += bf_lo(w.z)*hb.x + bf_hi(w.z)*hb.y + bf_lo(w.w)*hb.z + bf_hi(w.w)*hb.w;
      }
      const uint4*  wh  = (const uint4*)(whh2_lds + lr * 1024);
      const float4* h2p = (const float4*)h2_loc;
      #pragma unroll
      for (int q = 0; q < 4; ++q) {
        uint4  w  = wh[lane + 64 * q];
        float4 ha = h2p[2 * (lane + 64 * q)];
        float4 hb = h2p[2 * (lane + 64 * q) + 1];
        s += bf_lo(w.x)*ha.x + bf_hi(w.x)*ha.y + bf_lo(w.y)*ha.z + bf_hi(w.y)*ha.w;
        s += bf_lo(w.z)*hb.x + bf_hi(w.z)*hb.y + bf_lo(w.w)*hb.z + bf_hi(w.w)*hb.w;
      }
      s = wave_reduce(s);
      if (lane == 0) gsum2[lr] = s;
    }
    __syncthreads();
    if (tid < 8) {
      int uu = tid;
      float gi = sigmoidf_(gsum2[uu]      + b2v[uu]);
      float gf = sigmoidf_(gsum2[8 + uu]  + b2v[8 + uu]);
      float gg = tanhf    (gsum2[16 + uu] + b2v[16 + uu]);
      float go = sigmoidf_(gsum2[24 + uu] + b2v[24 + uu]);
      float c = gf * c2v[uu] + gi * gg;
      c2v[uu] = c;
      float h = go * tanhf(c);
      h2own[uu] = h;
      h2_buf[par * HID2 + 8 * b + uu] = h;          // plain store
    }
    __syncthreads();
    if (tid == 0) {
      float po = 0.f;
      #pragma unroll
      for (int uu = 0; uu < 8; ++uu) po += h2own[uu] * woutv[uu];
      partial_out[(int64_t)t * NCU + b] = po;
      __threadfence();
      __hip_atomic_store(&flag2[b], target, __ATOMIC_RELEASE, __HIP_MEMORY_SCOPE_AGENT);
    }
    if (tid < NCU) {
      while (__hip_atomic_load(&flag2[tid], __ATOMIC_RELAXED, __HIP_MEMORY_SCOPE_AGENT) < target)
        __builtin_amdgcn_s_sleep(2);
    }
    __syncthreads();
    __threadfence();
    {
      const float4* src = (const float4*)(h2_buf + par * HID2);
      float4* dst = (float4*)h2_loc;
      for (int i = tid; i < HID2 / 4; i += TPB) dst[i] = src[i];
    }
    __syncthreads();
  }
}

// ---------------------------------------------------------------------------
// out[t] = sum_b partial_out[t][b] + bout
// ---------------------------------------------------------------------------
__global__ void out_reduce(const float* __restrict__ partial_out,
                           const float* __restrict__ bout,
                           float* __restrict__ out)
{
  int t = blockIdx.x;
  int lane = threadIdx.x;   // 64 threads
  float s = 0.f;
  #pragma unroll
  for (int q = 0; q < 4; ++q) s += partial_out[(int64_t)t * NCU + lane + 64 * q];
  s = wave_reduce(s);
  if (lane == 0) out[t] = s + bout[0];
}

extern "C" void kernel_launch(void* const* d_in, const int* in_sizes, int n_in,
                              void* d_out, int out_size, void* d_ws, size_t ws_size,
                              hipStream_t stream)
{
  const float* x    = (const float*)d_in[0];
  const float* Wih1 = (const float*)d_in[1];
  const float* Whh1 = (const float*)d_in[2];
  const float* b1   = (const float*)d_in[3];
  const float* Wih2 = (const float*)d_in[4];
  const float* Whh2 = (const float*)d_in[5];
  const float* b2   = (const float*)d_in[6];
  const float* Wout = (const float*)d_in[7];
  const float* bout = (const float*)d_in[8];
  float* out = (float*)d_out;

  char* ws = (char*)d_ws;
  size_t off = 0;
  auto take = [&](size_t bytes) -> char* {
    char* p = ws + off;
    off = (off + bytes + 255) & ~(size_t)255;
    return p;
  };
  uint32_t* wih2_bf    = (uint32_t*)take((size_t)G2 * IN_DIM / 2 * 4); // 16.8 MB
  float*    h1_buf     = (float*)take(2 * HID1 * 4);
  float*    h2_buf     = (float*)take(2 * HID2 * 4);
  int*      flag1      = (int*)take(NCU * 4);
  int*      flag2      = (int*)take(NCU * 4);
  float*    partial_out= (float*)take((size_t)T_STEPS * NCU * 4);      // 2 MB

  if (off > ws_size) return;   // ws too small -> distinct failure signature

  hipLaunchKernelGGL(prep_kernel, dim3(1024), dim3(256), 0, stream,
                     Wih2, wih2_bf, h1_buf, h2_buf, flag1, flag2);

  void* args[] = { &x, &Wih1, &Whh1, &b1, &Whh2, &b2, &Wout, &wih2_bf,
                   &h1_buf, &h2_buf, &flag1, &flag2, &partial_out };
  hipLaunchCooperativeKernel((void*)lstm_persist, dim3(NCU), dim3(TPB),
                             args, 0, stream);

  hipLaunchKernelGGL(out_reduce, dim3(T_STEPS), dim3(64), 0, stream,
                     partial_out, bout, out);
}

// Round 3
// 14140.829 us; speedup vs baseline: 12.6330x; 12.6330x over previous
//
#include <hip/hip_runtime.h>
#include <stdint.h>

#define NCU 256
#define TPB 512
#define IN_DIM 1024
#define HID1   1024
#define HID2   2048
#define T_STEPS 2048

typedef float    f32x4 __attribute__((ext_vector_type(4)));
typedef uint32_t u32x4 __attribute__((ext_vector_type(4)));

__device__ __forceinline__ float bf_lo(uint32_t u){ return __uint_as_float(u << 16); }
__device__ __forceinline__ float bf_hi(uint32_t u){ return __uint_as_float(u & 0xffff0000u); }
__device__ __forceinline__ uint32_t f2bf(float f){
  uint32_t x = __float_as_uint(f);
  return (x + 0x7fffu + ((x >> 16) & 1u)) >> 16;   // RNE
}
__device__ __forceinline__ uint32_t pack2(float a, float b){
  return f2bf(a) | (f2bf(b) << 16);
}
__device__ __forceinline__ float wave_reduce(float v){
  v += __shfl_xor(v, 32); v += __shfl_xor(v, 16); v += __shfl_xor(v, 8);
  v += __shfl_xor(v, 4);  v += __shfl_xor(v, 2);  v += __shfl_xor(v, 1);
  return v;
}
__device__ __forceinline__ float sigmoidf_(float x){ return 1.0f / (1.0f + expf(-x)); }

// ---------------------------------------------------------------------------
// prep: zero the combined exchange lines (flags + data) with agent-coherent
// stores. Runs every launch (replay-deterministic).
// ---------------------------------------------------------------------------
__global__ void prep_kernel(float* __restrict__ combined)
{
  int idx = blockIdx.x * blockDim.x + threadIdx.x;
  const int total = 2 * NCU * 16;
  for (int i = idx; i < total; i += gridDim.x * blockDim.x)
    __hip_atomic_store(combined + i, 0.f, __ATOMIC_RELAXED, __HIP_MEMORY_SCOPE_AGENT);
}

// ---------------------------------------------------------------------------
// persistent 2-layer LSTM scan. 256 blocks (1/CU) x 512 threads.
// Block b owns layer1 units [4b,4b+4) and layer2 units [8b,8b+8).
// One global sync per iteration; iteration t computes h1[t] and h2[t-1].
// Exchange line (64 B) per block: dw[0..3]=h1own, dw[4..11]=h2own, dw[12]=flag.
// All cross-CU traffic uses sc0/sc1 (L3-coherent) accesses: NO cache
// maintenance ops (buffer_wbl2 / buffer_inv) anywhere in the loop.
// ---------------------------------------------------------------------------
__global__ __launch_bounds__(TPB, 1) void lstm_persist(
    const float* __restrict__ x,    const float* __restrict__ Wih1,
    const float* __restrict__ Whh1, const float* __restrict__ b1,
    const float* __restrict__ Wih2, const float* __restrict__ Whh2,
    const float* __restrict__ b2,   const float* __restrict__ Wout,
    float* __restrict__ combined,   float* __restrict__ partial_out)
{
  // 128 KiB: 32 rows x 256 u32x4; u4 index u holds elements [4u..4u+3] and
  // [1024+4u..1024+4u+3] of the row -> all per-step LDS reads are contiguous.
  __shared__ u32x4 whh2_u4[32 * 256];
  __shared__ f32x4 h1_4[HID1 / 4];   // h1[t-1] (4 KiB)
  __shared__ f32x4 h2_4[HID2 / 4];   // h2[t-2] (8 KiB)
  __shared__ float gsum1[16], gx1v[16], gsum2[32], b2v[32];

  const int b    = blockIdx.x;
  const int tid  = threadIdx.x;
  const int lane = tid & 63;
  const int wv   = tid >> 6;   // 8 waves
  float* h1_loc = (float*)h1_4;
  float* h2_loc = (float*)h2_4;

  // ---- init: stage Whh2 slice into LDS (fp32 -> bf16, paired-block layout) --
  for (int i = tid; i < 32 * 256; i += TPB) {
    int lr = i >> 8, u = i & 255;
    int g = lr >> 3, uu2 = lr & 7;
    const f32x4* s4 = (const f32x4*)(Whh2 + (int64_t)(g * HID2 + 8 * b + uu2) * HID2);
    f32x4 lo = s4[u], hi = s4[256 + u];
    u32x4 wv4;
    wv4[0] = pack2(lo[0], lo[1]); wv4[1] = pack2(lo[2], lo[3]);
    wv4[2] = pack2(hi[0], hi[1]); wv4[3] = pack2(hi[2], hi[3]);
    whh2_u4[i] = wv4;
  }

  // ---- Whh1 slice in registers (fp32, 2 rows/wave, 16 elems/lane/row) ----
  float w1r[2][16];
  int rows1[2];
  #pragma unroll
  for (int rr = 0; rr < 2; ++rr) {
    int lr1 = wv * 2 + rr;
    int g = lr1 >> 2, uu = lr1 & 3;
    int row = g * HID1 + 4 * b + uu;
    rows1[rr] = row;
    #pragma unroll
    for (int j = 0; j < 16; ++j)
      w1r[rr][j] = Whh1[(int64_t)row * IN_DIM + lane + 64 * j];
  }

  // ---- Wih2 slice in registers (bf16 packed, paired-block layout) ----
  // 4 rows/wave, 2 u32x4 per row per lane = 32 VGPRs.
  u32x4 wi_reg[4][2];
  #pragma unroll
  for (int rr = 0; rr < 4; ++rr) {
    int lr = wv * 4 + rr;
    int g = lr >> 3, uu = lr & 7;
    const f32x4* s4 = (const f32x4*)(Wih2 + (int64_t)(g * HID2 + 8 * b + uu) * IN_DIM);
    #pragma unroll
    for (int q = 0; q < 2; ++q) {
      int u = lane + 64 * q;
      f32x4 lo = s4[u], hi = s4[128 + u];
      u32x4 wv4;
      wv4[0] = pack2(lo[0], lo[1]); wv4[1] = pack2(lo[2], lo[3]);
      wv4[2] = pack2(hi[0], hi[1]); wv4[3] = pack2(hi[2], hi[3]);
      wi_reg[rr][q] = wv4;
    }
  }

  // ---- gx1 = Wih1 @ x + b1 (constant over t) ----
  #pragma unroll
  for (int rr = 0; rr < 2; ++rr) {
    int row = rows1[rr];
    float s = 0.f;
    #pragma unroll
    for (int j = 0; j < 16; ++j)
      s += Wih1[(int64_t)row * IN_DIM + lane + 64 * j] * x[lane + 64 * j];
    s = wave_reduce(s);
    if (lane == 0) gx1v[wv * 2 + rr] = s + b1[row];
  }
  if (tid < 32) { int g = tid >> 3, uu = tid & 7; b2v[tid] = b2[g * HID2 + 8 * b + uu]; }
  for (int i = tid; i < HID1; i += TPB) h1_loc[i] = 0.f;
  for (int i = tid; i < HID2; i += TPB) h2_loc[i] = 0.f;

  const float woutreg = Wout[8 * b + (lane & 7)];
  float c1reg = 0.f, c2reg = 0.f;
  __syncthreads();

  // ---- time loop: iteration t computes h1[t] (t<T) and h2[t-1] (t>0) ----
  for (int t = 0; t <= T_STEPS; ++t) {
    const int par = t & 1;

    if (t < T_STEPS) {
      // Phase A: layer1 recurrent matvec over h1[t-1]
      #pragma unroll
      for (int rr = 0; rr < 2; ++rr) {
        float s = 0.f;
        #pragma unroll
        for (int j = 0; j < 16; ++j) s += w1r[rr][j] * h1_loc[lane + 64 * j];
        s = wave_reduce(s);
        if (lane == 0) gsum1[wv * 2 + rr] = s;
      }
    }
    if (t > 0) {
      // Phase B: layer2 matvec: Wih2(reg bf16)*h1[t-1] + Whh2(LDS bf16)*h2[t-2]
      #pragma unroll
      for (int rr = 0; rr < 4; ++rr) {
        const int lr = wv * 4 + rr;
        float s = 0.f;
        #pragma unroll
        for (int q = 0; q < 2; ++q) {
          const int u = lane + 64 * q;
          u32x4 w = wi_reg[rr][q];
          f32x4 ha = h1_4[u];
          f32x4 hb = h1_4[128 + u];
          s += bf_lo(w[0]) * ha[0] + bf_hi(w[0]) * ha[1]
             + bf_lo(w[1]) * ha[2] + bf_hi(w[1]) * ha[3];
          s += bf_lo(w[2]) * hb[0] + bf_hi(w[2]) * hb[1]
             + bf_lo(w[3]) * hb[2] + bf_hi(w[3]) * hb[3];
        }
        #pragma unroll
        for (int q = 0; q < 4; ++q) {
          const int u = lane + 64 * q;
          u32x4 w = whh2_u4[lr * 256 + u];
          f32x4 ha = h2_4[u];
          f32x4 hb = h2_4[256 + u];
          s += bf_lo(w[0]) * ha[0] + bf_hi(w[0]) * ha[1]
             + bf_lo(w[1]) * ha[2] + bf_hi(w[1]) * ha[3];
          s += bf_lo(w[2]) * hb[0] + bf_hi(w[2]) * hb[1]
             + bf_lo(w[3]) * hb[2] + bf_hi(w[3]) * hb[3];
        }
        s = wave_reduce(s);
        if (lane == 0) gsum2[lr] = s;
      }
    }
    __syncthreads();   // gsums visible to wave 0

    if (wv == 0) {
      float h1v = 0.f;
      if (t < T_STEPS) {
        const int u1 = lane & 3;
        float gi = sigmoidf_(gsum1[u1]      + gx1v[u1]);
        float gf = sigmoidf_(gsum1[4 + u1]  + gx1v[4 + u1]);
        float gg = tanhf    (gsum1[8 + u1]  + gx1v[8 + u1]);
        float go = sigmoidf_(gsum1[12 + u1] + gx1v[12 + u1]);
        c1reg = gf * c1reg + gi * gg;
        h1v = go * tanhf(c1reg);               // valid in lanes 0..3
      }
      float h2v = 0.f;
      if (t > 0) {
        const int u2 = lane & 7;
        float gi = sigmoidf_(gsum2[u2]      + b2v[u2]);
        float gf = sigmoidf_(gsum2[8 + u2]  + b2v[8 + u2]);
        float gg = tanhf    (gsum2[16 + u2] + b2v[16 + u2]);
        float go = sigmoidf_(gsum2[24 + u2] + b2v[24 + u2]);
        c2reg = gf * c2reg + gi * gg;
        h2v = go * tanhf(c2reg);               // valid in lanes 0..7
        float contrib = (lane < 8) ? h2v * woutreg : 0.f;
        float po = wave_reduce(contrib);
        if (lane == 0) partial_out[(int64_t)(t - 1) * NCU + b] = po;
      }
      if (t < T_STEPS) {
        // publish: lanes 0..2 store 16B each, then flag (all sc0/sc1, no fences)
        float* lineW = combined + ((size_t)par * NCU + b) * 16;
        f32x4 st;
        const int base = (lane == 2) ? 4 : 0;
        #pragma unroll
        for (int c2 = 0; c2 < 4; ++c2) {
          float a  = __shfl(h1v, c2);
          float bb = __shfl(h2v, base + c2);
          st[c2] = (lane == 0) ? a : bb;
        }
        float* p = lineW + 4 * lane;
        if (lane < 3)
          asm volatile("global_store_dwordx4 %0, %1, off sc0 sc1"
                       :: "v"(p), "v"(st) : "memory");
        asm volatile("s_waitcnt vmcnt(0)" ::: "memory");
        if (lane == 0)
          __hip_atomic_store((int*)(lineW + 12), t + 1,
                             __ATOMIC_RELAXED, __HIP_MEMORY_SCOPE_AGENT);
      }
    }

    if (t < T_STEPS) {
      // waves 4..7: poll one flag each (overlaps wave0's gate computation)
      if (tid >= NCU) {
        const int target = t + 1;
        const int* fp = (const int*)(combined + ((size_t)par * NCU + (tid - NCU)) * 16 + 12);
        while (__hip_atomic_load(fp, __ATOMIC_RELAXED, __HIP_MEMORY_SCOPE_AGENT) < target)
          __builtin_amdgcn_s_sleep(1);
      }
      __syncthreads();
      // waves 0..3: gather all 256 lines into LDS (coherent sc0/sc1 loads)
      if (tid < NCU) {
        const float* line = combined + ((size_t)par * NCU + tid) * 16;
        f32x4 a, bb, cc;
        asm volatile("global_load_dwordx4 %0, %1, off sc0 sc1"
                     : "=&v"(a)  : "v"(line));
        asm volatile("global_load_dwordx4 %0, %1, off offset:16 sc0 sc1"
                     : "=&v"(bb) : "v"(line));
        asm volatile("global_load_dwordx4 %0, %1, off offset:32 sc0 sc1"
                     : "=&v"(cc) : "v"(line));
        asm volatile("s_waitcnt vmcnt(0)" ::: "memory");
        h1_4[tid]         = a;
        h2_4[2 * tid]     = bb;
        h2_4[2 * tid + 1] = cc;
      }
      __syncthreads();
    }
  }
}

// ---------------------------------------------------------------------------
// out[t] = sum_b partial_out[t][b] + bout
// ---------------------------------------------------------------------------
__global__ void out_reduce(const float* __restrict__ partial_out,
                           const float* __restrict__ bout,
                           float* __restrict__ out)
{
  int t = blockIdx.x;
  int lane = threadIdx.x;   // 64 threads
  float s = 0.f;
  #pragma unroll
  for (int q = 0; q < 4; ++q) s += partial_out[(int64_t)t * NCU + lane + 64 * q];
  s = wave_reduce(s);
  if (lane == 0) out[t] = s + bout[0];
}

extern "C" void kernel_launch(void* const* d_in, const int* in_sizes, int n_in,
                              void* d_out, int out_size, void* d_ws, size_t ws_size,
                              hipStream_t stream)
{
  const float* x    = (const float*)d_in[0];
  const float* Wih1 = (const float*)d_in[1];
  const float* Whh1 = (const float*)d_in[2];
  const float* b1   = (const float*)d_in[3];
  const float* Wih2 = (const float*)d_in[4];
  const float* Whh2 = (const float*)d_in[5];
  const float* b2   = (const float*)d_in[6];
  const float* Wout = (const float*)d_in[7];
  const float* bout = (const float*)d_in[8];
  float* out = (float*)d_out;

  char* ws = (char*)d_ws;
  size_t off = 0;
  auto take = [&](size_t bytes) -> char* {
    char* p = ws + off;
    off = (off + bytes + 255) & ~(size_t)255;
    return p;
  };
  float* combined    = (float*)take((size_t)2 * NCU * 16 * 4);        // 32 KB
  float* partial_out = (float*)take((size_t)T_STEPS * NCU * 4);       // 2 MB

  if (off > ws_size) return;

  hipLaunchKernelGGL(prep_kernel, dim3(8), dim3(256), 0, stream, combined);

  void* args[] = { &x, &Wih1, &Whh1, &b1, &Wih2, &Whh2, &b2, &Wout,
                   &combined, &partial_out };
  (void)hipLaunchCooperativeKernel((void*)lstm_persist, dim3(NCU), dim3(TPB),
                                   args, 0, stream);

  hipLaunchKernelGGL(out_reduce, dim3(T_STEPS), dim3(64), 0, stream,
                     partial_out, bout, out);
}